// Round 7
// baseline (409.086 us; speedup 1.0000x reference)
//
#include <hip/hip_runtime.h>
#include <stdint.h>

// F=16, N=8192, D=64, K=512. Buffers fp32 in/out. Target: BIT-EXACT emulation of the
// numpy-fp32 referee: distances = fl(fl(xsq - fl(2*dot)) + wsq), dot = seq-d mul/add,
// xsq = numpy pairwise 8-acc tree, wsq = seq-d, first-index argmin.
#define F_ 16
#define N_ 8192
#define D_ 64
#define K_ 512
#define TK 128
#define PAD 68

__global__ __launch_bounds__(256) void vq_main(const float* __restrict__ x,
                                               const float* __restrict__ w,
                                               float* __restrict__ out,
                                               double* __restrict__ lacc) {
    #pragma clang fp contract(off)
    __shared__ float wt[TK][PAD];
    __shared__ float wsq[TK];

    const int tid = threadIdx.x;
    const int f = blockIdx.x >> 5;                       // 32 blocks per f
    const int point = blockIdx.x * 256 + tid;
    const float* wf = w + (size_t)f * D_ * K_;           // [D][K] slab

    // x -> registers (raw fp32)
    float xr[D_];
    {
        const float4* xv = (const float4*)(x + (size_t)point * D_);
        #pragma unroll
        for (int i = 0; i < D_ / 4; ++i) {
            float4 u = xv[i];
            xr[4*i+0] = u.x; xr[4*i+1] = u.y; xr[4*i+2] = u.z; xr[4*i+3] = u.w;
        }
    }

    // xsq: numpy pairwise_sum scalar base case for n=64 on sq[d]=fl(x*x):
    // r[j]=sq[j]; r[j]+=sq[8i+j]; res=((r0+r1)+(r2+r3))+((r4+r5)+(r6+r7))
    float xsq;
    {
        float r[8];
        #pragma unroll
        for (int j = 0; j < 8; ++j) r[j] = __fmul_rn(xr[j], xr[j]);
        #pragma unroll
        for (int i = 8; i < 64; i += 8)
            #pragma unroll
            for (int j = 0; j < 8; ++j)
                r[j] = __fadd_rn(r[j], __fmul_rn(xr[i+j], xr[i+j]));
        float c01 = __fadd_rn(r[0], r[1]), c23 = __fadd_rn(r[2], r[3]);
        float c45 = __fadd_rn(r[4], r[5]), c67 = __fadd_rn(r[6], r[7]);
        xsq = __fadd_rn(__fadd_rn(c01, c23), __fadd_rn(c45, c67));
    }

    float best = 3.4e38f;
    int bestk = 0;

    for (int k0 = 0; k0 < K_; k0 += TK) {
        __syncthreads();   // WAR on previous tile
        for (int e = tid; e < D_ * TK; e += 256) {       // stage raw W tile
            int d = e >> 7, j = e & (TK - 1);
            wt[j][d] = wf[(size_t)d * K_ + (k0 + j)];
        }
        __syncthreads();
        if (tid < TK) {    // wsq: SEQUENTIAL over d of fl(w*w) (numpy non-last-axis reduce)
            float s = 0.f;
            #pragma unroll
            for (int d = 0; d < D_; ++d)
                s = __fadd_rn(s, __fmul_rn(wt[tid][d], wt[tid][d]));
            wsq[tid] = s;
        }
        __syncthreads();

        #pragma unroll 2
        for (int j = 0; j < TK; ++j) {
            const float4* row = (const float4*)(&wt[j][0]);   // wave-uniform -> broadcast
            // dot: SEQUENTIAL d=0..63, acc = fl(acc + fl(x*w))  (numpy einsum SOP kernel)
            float acc = 0.f;
            #pragma unroll
            for (int i = 0; i < 16; ++i) {
                float4 wv = row[i];
                acc = __fadd_rn(acc, __fmul_rn(xr[4*i + 0], wv.x));
                acc = __fadd_rn(acc, __fmul_rn(xr[4*i + 1], wv.y));
                acc = __fadd_rn(acc, __fmul_rn(xr[4*i + 2], wv.z));
                acc = __fadd_rn(acc, __fmul_rn(xr[4*i + 3], wv.w));
            }
            // distance = fl(fl(xsq - fl(2*dot)) + wsq)
            float s = __fadd_rn(__fsub_rn(xsq, __fmul_rn(2.0f, acc)), wsq[j]);
            if (s < best) { best = s; bestk = k0 + j; }   // first-index argmin
        }
    }

    // Gather raw codebook, STE output fl(x + fl(q-x)), fp64 loss accumulation.
    double lsum = 0.0;
    float ov[D_];
    #pragma unroll
    for (int d = 0; d < D_; ++d) {
        float q = wf[(size_t)d * K_ + bestk];
        float e = __fsub_rn(q, xr[d]);                    // also the loss term base
        ov[d] = __fadd_rn(xr[d], e);                      // STE forward value
        float sq = __fmul_rn(e, e);
        lsum += (double)sq;
    }
    float4* ovv = (float4*)(out + (size_t)point * D_);
    #pragma unroll
    for (int i = 0; i < D_ / 4; ++i)
        ovv[i] = make_float4(ov[4*i+0], ov[4*i+1], ov[4*i+2], ov[4*i+3]);

    #pragma unroll
    for (int off = 32; off >= 1; off >>= 1)
        lsum += __shfl_down(lsum, off);
    if ((tid & 63) == 0)
        atomicAdd(lacc, lsum);
}

// loss = fl(m + fl(0.25*m)), m = fp32(mean((q-x)^2))
__global__ void vq_finalize(const double* __restrict__ lacc, float* __restrict__ out) {
    #pragma clang fp contract(off)
    double m64 = lacc[0] / (double)((size_t)F_ * N_ * D_);
    float m = (float)m64;
    out[0] = __fadd_rn(m, __fmul_rn(0.25f, m));
}

extern "C" void kernel_launch(void* const* d_in, const int* in_sizes, int n_in,
                              void* d_out, int out_size, void* d_ws, size_t ws_size,
                              hipStream_t stream) {
    const float* x = (const float*)d_in[0];   // fp32 [F,N,D]
    const float* w = (const float*)d_in[1];   // fp32 [F,D,K]
    if (in_sizes[0] == F_ * D_ * K_ && in_sizes[1] == F_ * N_ * D_) {
        x = (const float*)d_in[1];
        w = (const float*)d_in[0];
    }
    float* out = (float*)d_out;               // fp32 [F*N*D + 1]

    double* lacc = (double*)d_ws;
    hipMemsetAsync(lacc, 0, sizeof(double), stream);
    vq_main<<<(F_ * N_) / 256, 256, 0, stream>>>(x, w, out, lacc);
    vq_finalize<<<1, 1, 0, stream>>>(lacc, out + (size_t)F_ * N_ * D_);
}